// Round 11
// baseline (1808.100 us; speedup 1.0000x reference)
//
#include <hip/hip_runtime.h>
#include <cstdint>

typedef _Float16 f16x2 __attribute__((ext_vector_type(2)));
typedef _Float16 half8 __attribute__((ext_vector_type(8)));
typedef float f32x4 __attribute__((ext_vector_type(4)));

// Clamp-free fast activations: gate pre-activations here are |x| <~ 15.
__device__ __forceinline__ float fsig(float x) {
  return __fdividef(1.f, 1.f + __expf(-x));
}
__device__ __forceinline__ float ftanh_(float x) {
  return fmaf(2.f, fsig(x + x), -1.f);
}
__device__ __forceinline__ int packf16(float a, float b) {
  f16x2 p; p.x = (_Float16)a; p.y = (_Float16)b;
  return __builtin_bit_cast(int, p);
}
__device__ __forceinline__ float dot2(int w, int h, float acc) {
  return __builtin_amdgcn_fdot2(__builtin_bit_cast(f16x2, w),
                                __builtin_bit_cast(f16x2, h), acc, false);
}

// ---------------------------------------------------------------------------
// Layer 1: unchanged from R10 (~85 us) to keep attribution on lstm2.
// ---------------------------------------------------------------------------
__global__ __launch_bounds__(256, 2) void lstm1_kernel(
    const float* __restrict__ x, const float* __restrict__ Wih,
    const float* __restrict__ Whh, const float* __restrict__ bih,
    const float* __restrict__ bhh, int4* __restrict__ h1out) {
  const int n = blockIdx.x * 256 + threadIdx.x;  // chain id = b*S + s

  int whh2[128];
#pragma unroll
  for (int r = 0; r < 32; ++r) {
#pragma unroll
    for (int j = 0; j < 4; ++j) {
      float2 v = ((const float2*)(Whh + r * 8))[j];
      whh2[r * 4 + j] = packf16(v.x, v.y);
    }
  }
  int wxb[32];
#pragma unroll
  for (int r = 0; r < 32; ++r) wxb[r] = packf16(Wih[r], bih[r] + bhh[r]);

#pragma unroll
  for (int i = 0; i < 128; i += 8)
    asm volatile("" : "+v"(whh2[i]), "+v"(whh2[i + 1]), "+v"(whh2[i + 2]),
                      "+v"(whh2[i + 3]), "+v"(whh2[i + 4]), "+v"(whh2[i + 5]),
                      "+v"(whh2[i + 6]), "+v"(whh2[i + 7]));
#pragma unroll
  for (int i = 0; i < 32; i += 8)
    asm volatile("" : "+v"(wxb[i]), "+v"(wxb[i + 1]), "+v"(wxb[i + 2]),
                      "+v"(wxb[i + 3]), "+v"(wxb[i + 4]), "+v"(wxb[i + 5]),
                      "+v"(wxb[i + 6]), "+v"(wxb[i + 7]));

  const float* __restrict__ xp = x + (size_t)n * 16;
  float c[8];
  int h2[4];
#pragma unroll
  for (int k = 0; k < 8; ++k) c[k] = 0.f;
#pragma unroll
  for (int j = 0; j < 4; ++j) h2[j] = 0;

  float xv = xp[0];
#pragma unroll 1
  for (int t = 0; t < 16; ++t) {
    float xn = xp[(t + 1) & 15];
    const int xt1 = packf16(xv, 1.f);
    float hn[8];
#pragma unroll
    for (int k = 0; k < 8; ++k) {
      float acc[4];
#pragma unroll
      for (int gi = 0; gi < 4; ++gi) {
        const int r = gi * 8 + k;
        float a = dot2(wxb[r], xt1, 0.f);
        a = dot2(whh2[r * 4 + 0], h2[0], a);
        a = dot2(whh2[r * 4 + 1], h2[1], a);
        a = dot2(whh2[r * 4 + 2], h2[2], a);
        a = dot2(whh2[r * 4 + 3], h2[3], a);
        acc[gi] = a;
      }
      float iv = fsig(acc[0]), fv = fsig(acc[1]);
      float gv = ftanh_(acc[2]), ov = fsig(acc[3]);
      c[k] = fmaf(fv, c[k], iv * gv);
      hn[k] = ov * ftanh_(c[k]);
    }
#pragma unroll
    for (int j = 0; j < 4; ++j) h2[j] = packf16(hn[2 * j], hn[2 * j + 1]);
    xv = xn;
  }
  int4 o;
  o.x = h2[0]; o.y = h2[1]; o.z = h2[2]; o.w = h2[3];
  h1out[n] = o;
}

// ---------------------------------------------------------------------------
// Pack kernel: A-fragments for lstm2's MFMA in exact lane order.
// Thread t (wave j=t>>6, lane, quad=lane>>4, mA=lane&15) supplies
// A[m=mA][k=quad*8+0..7] of M-tiles {g*8+j : g=0..3} x K-tiles 0..4, where
// K-tile 4 holds Wih (k=128..135) zero-padded to 160. Also per-thread biases
// for the C cells it will own (rows quad*4+r, m = 16j+quad*4+r).
// ---------------------------------------------------------------------------
__global__ __launch_bounds__(512) void pack2_kernel(
    const float* __restrict__ Wih, const float* __restrict__ Whh,
    const float* __restrict__ bih, const float* __restrict__ bhh,
    int* __restrict__ wpack, float* __restrict__ bpack) {
  const int t = threadIdx.x;
  const int j = t >> 6, lane = t & 63, quad = lane >> 4, mA = lane & 15;
  const int kA = quad * 8;
  int* wp = wpack + t * 80;
#pragma unroll
  for (int g = 0; g < 4; ++g) {
    const int row = g * 128 + 16 * j + mA;  // gate-row in [0,512)
#pragma unroll
    for (int kt = 0; kt < 4; ++kt) {
      const float* src = Whh + (size_t)row * 128 + kt * 32 + kA;
#pragma unroll
      for (int pq = 0; pq < 4; ++pq)
        wp[(g * 5 + kt) * 4 + pq] = packf16(src[2 * pq], src[2 * pq + 1]);
    }
    if (quad == 0) {  // K-tile 4: k=128..135 -> Wih; other quads: zero pad
      const float* xi = Wih + (size_t)row * 8;
#pragma unroll
      for (int pq = 0; pq < 4; ++pq)
        wp[(g * 5 + 4) * 4 + pq] = packf16(xi[2 * pq], xi[2 * pq + 1]);
    } else {
#pragma unroll
      for (int pq = 0; pq < 4; ++pq) wp[(g * 5 + 4) * 4 + pq] = 0;
    }
  }
  float* bp = bpack + t * 16;
  const int mC = 16 * j + quad * 4;
#pragma unroll
  for (int g = 0; g < 4; ++g)
#pragma unroll
    for (int r = 0; r < 4; ++r)
      bp[g * 4 + r] = bih[g * 128 + mC + r] + bhh[g * 128 + mC + r];
}

// ---------------------------------------------------------------------------
// Layer 2 via MFMA: 16 blocks x 512 thr, 16 batches/block. Per step one
// mfma-GEMM G[512x16] = W[512x160] * [h;x;0][160x16] (f16, fp32 acc):
// wave j does M-tiles {j, 8+j, 16+j, 24+j} x 5 K-tiles = 20 MFMA.
// Rationale: R4..R10 proved the allocator parks loop-spanning operands in
// AGPRs and charges v_accvgpr_read per use on the VALU path; MFMA reads
// AGPRs natively, so the A-frags (volatile-loaded, non-rematerializable)
// cost nothing per use. h lives in LDS [16][168] f16 double-buffered;
// B-frag = 1 ds_read_b128 per K-tile. Lane owns C cells (m=16j+quad*4+r,
// n=lane&15): c-state in 4 VGPRs. One barrier/step.
// ---------------------------------------------------------------------------
__global__ __launch_bounds__(512, 2) void lstm2_kernel(
    const int4* __restrict__ h1, const int* __restrict__ wpack,
    const float* __restrict__ bpack, const float* __restrict__ Wd1,
    const float* __restrict__ bd1, const float* __restrict__ Wd2,
    const float* __restrict__ bd2, float* __restrict__ out) {
  __shared__ __align__(16) _Float16 H[2][16][168];  // [buf][batch][k], 10.5 KB
  const int t = threadIdx.x;
  const int j = t >> 6, lane = t & 63, quad = lane >> 4, n = lane & 15;
  const int m0 = 16 * j + quad * 4;  // first hidden index of this lane's cells
  const int bb0 = blockIdx.x * 16;   // first batch of this block

  // A-frags: volatile loads (exactly once, final f16-packed form; nothing to
  // rematerialize). 20 frags x int4.
  int4 wfrag[20];
  {
    const volatile int4* wp = (const volatile int4*)(wpack + t * 80);
#pragma unroll
    for (int i = 0; i < 20; ++i) {
      int4 v; v.x = wp[i].x; v.y = wp[i].y; v.z = wp[i].z; v.w = wp[i].w;
      wfrag[i] = v;
    }
  }
  float bias[16];
  {
    const volatile float* bp = bpack + t * 16;
#pragma unroll
    for (int i = 0; i < 16; ++i) bias[i] = bp[i];
  }

  // zero both buffers (h area, x area, pads)
  {
    int* Hi = (int*)H;  // 2*16*168*2 B = 2688 ints
    for (int i = t; i < 2688; i += 512) Hi[i] = 0;
  }
  __syncthreads();
  if (t < 16)  // x_0 for batch t of this block
    *(int4*)&H[0][t][128] = h1[(size_t)(bb0 + t) * 1024];
  __syncthreads();

  float cst[4] = {0.f, 0.f, 0.f, 0.f};
  int p = 0;

#pragma unroll 1
  for (int ts = 0; ts < 1024; ++ts) {
    int4 xnext = {0, 0, 0, 0};
    if (t < 16)  // prefetch x_{ts+1} (L2-hot; overlaps the MFMA block)
      xnext = h1[(size_t)(bb0 + t) * 1024 + (ts < 1023 ? ts + 1 : 1023)];

    // B-frags from LDS: H[p][n][kt*32 + quad*8 .. +7]
    half8 bf0 = *(const half8*)&H[p][n][0 * 32 + quad * 8];
    half8 bf1 = *(const half8*)&H[p][n][1 * 32 + quad * 8];
    half8 bf2 = *(const half8*)&H[p][n][2 * 32 + quad * 8];
    half8 bf3 = *(const half8*)&H[p][n][3 * 32 + quad * 8];
    half8 bf4 = *(const half8*)&H[p][n][4 * 32 + quad * 8];

    f32x4 acc[4];
#pragma unroll
    for (int g = 0; g < 4; ++g) {
      f32x4 a = {0.f, 0.f, 0.f, 0.f};
      a = __builtin_amdgcn_mfma_f32_16x16x32_f16(
          __builtin_bit_cast(half8, wfrag[g * 5 + 0]), bf0, a, 0, 0, 0);
      a = __builtin_amdgcn_mfma_f32_16x16x32_f16(
          __builtin_bit_cast(half8, wfrag[g * 5 + 1]), bf1, a, 0, 0, 0);
      a = __builtin_amdgcn_mfma_f32_16x16x32_f16(
          __builtin_bit_cast(half8, wfrag[g * 5 + 2]), bf2, a, 0, 0, 0);
      a = __builtin_amdgcn_mfma_f32_16x16x32_f16(
          __builtin_bit_cast(half8, wfrag[g * 5 + 3]), bf3, a, 0, 0, 0);
      a = __builtin_amdgcn_mfma_f32_16x16x32_f16(
          __builtin_bit_cast(half8, wfrag[g * 5 + 4]), bf4, a, 0, 0, 0);
      acc[g] = a;
    }

    // state update for this lane's 4 cells (hidden m0+r, batch n)
    float hx[4];
#pragma unroll
    for (int r = 0; r < 4; ++r) {
      float iv = fsig(acc[0][r] + bias[0 * 4 + r]);
      float fv = fsig(acc[1][r] + bias[1 * 4 + r]);
      float gv = ftanh_(acc[2][r] + bias[2 * 4 + r]);
      float ov = fsig(acc[3][r] + bias[3 * 4 + r]);
      cst[r] = fmaf(fv, cst[r], iv * gv);
      hx[r] = ov * ftanh_(cst[r]);
    }
    // publish h into the next buffer (4 consecutive f16 = one b64 write)
    int2 hw;
    hw.x = packf16(hx[0], hx[1]);
    hw.y = packf16(hx[2], hx[3]);
    *(int2*)&H[1 - p][n][m0] = hw;
    if (t < 16) *(int4*)&H[1 - p][t][128] = xnext;  // x_{ts+1}
    __syncthreads();  // the only barrier per step
    p ^= 1;
  }

  // Epilogue: wave j handles batches 2j, 2j+1; lane = Wd1 row.
#pragma unroll
  for (int bi = 0; bi < 2; ++bi) {
    const int nn = 2 * j + bi;
    float a = bd1[lane];
    for (int k = 0; k < 128; ++k)
      a = fmaf(Wd1[lane * 128 + k], (float)H[p][nn][k], a);
    float v = a * Wd2[lane];
#pragma unroll
    for (int off = 32; off > 0; off >>= 1) v += __shfl_down(v, off);
    if (lane == 0) out[bb0 + nn] = v + bd2[0];
  }
}

extern "C" void kernel_launch(void* const* d_in, const int* in_sizes, int n_in,
                              void* d_out, int out_size, void* d_ws, size_t ws_size,
                              hipStream_t stream) {
  const float* x    = (const float*)d_in[0];
  // d_in[1] is the unused python scalar `data`
  const float* Wih1 = (const float*)d_in[2];
  const float* Whh1 = (const float*)d_in[3];
  const float* bih1 = (const float*)d_in[4];
  const float* bhh1 = (const float*)d_in[5];
  const float* Wih2 = (const float*)d_in[6];
  const float* Whh2 = (const float*)d_in[7];
  const float* bih2 = (const float*)d_in[8];
  const float* bhh2 = (const float*)d_in[9];
  const float* W1   = (const float*)d_in[10];
  const float* b1   = (const float*)d_in[11];
  const float* W2   = (const float*)d_in[12];
  const float* b2   = (const float*)d_in[13];
  float* out = (float*)d_out;

  // workspace layout
  char* ws = (char*)d_ws;
  int4*  h1    = (int4*)ws;                              // 4 MB
  int*   wpack = (int*)(ws + (4 << 20));                 // 512*80*4 = 160 KB
  float* bpack = (float*)(ws + (4 << 20) + (160 << 10)); // 32 KB

  lstm1_kernel<<<1024, 256, 0, stream>>>(x, Wih1, Whh1, bih1, bhh1, h1);
  pack2_kernel<<<1, 512, 0, stream>>>(Wih2, Whh2, bih2, bhh2, wpack, bpack);
  lstm2_kernel<<<16, 512, 0, stream>>>(h1, wpack, bpack, W1, b1, W2, b2, out);
}

// Round 12
// 1719.245 us; speedup vs baseline: 1.0517x; 1.0517x over previous
//
#include <hip/hip_runtime.h>
#include <cstdint>

typedef _Float16 f16x2 __attribute__((ext_vector_type(2)));
typedef _Float16 half8 __attribute__((ext_vector_type(8)));
typedef float f32x4 __attribute__((ext_vector_type(4)));

// Clamp-free fast activations: gate pre-activations here are |x| <~ 15.
__device__ __forceinline__ float fsig(float x) {
  return __fdividef(1.f, 1.f + __expf(-x));
}
__device__ __forceinline__ float ftanh_(float x) {
  return fmaf(2.f, fsig(x + x), -1.f);
}
__device__ __forceinline__ int packf16(float a, float b) {
  f16x2 p; p.x = (_Float16)a; p.y = (_Float16)b;
  return __builtin_bit_cast(int, p);
}
__device__ __forceinline__ float dot2(int w, int h, float acc) {
  return __builtin_amdgcn_fdot2(__builtin_bit_cast(f16x2, w),
                                __builtin_bit_cast(f16x2, h), acc, false);
}

// ---------------------------------------------------------------------------
// Layer 1: unchanged (byte-identical structure) to keep attribution on lstm2.
// ---------------------------------------------------------------------------
__global__ __launch_bounds__(256, 2) void lstm1_kernel(
    const float* __restrict__ x, const float* __restrict__ Wih,
    const float* __restrict__ Whh, const float* __restrict__ bih,
    const float* __restrict__ bhh, int4* __restrict__ h1out) {
  const int n = blockIdx.x * 256 + threadIdx.x;  // chain id = b*S + s

  int whh2[128];
#pragma unroll
  for (int r = 0; r < 32; ++r) {
#pragma unroll
    for (int j = 0; j < 4; ++j) {
      float2 v = ((const float2*)(Whh + r * 8))[j];
      whh2[r * 4 + j] = packf16(v.x, v.y);
    }
  }
  int wxb[32];
#pragma unroll
  for (int r = 0; r < 32; ++r) wxb[r] = packf16(Wih[r], bih[r] + bhh[r]);

#pragma unroll
  for (int i = 0; i < 128; i += 8)
    asm volatile("" : "+v"(whh2[i]), "+v"(whh2[i + 1]), "+v"(whh2[i + 2]),
                      "+v"(whh2[i + 3]), "+v"(whh2[i + 4]), "+v"(whh2[i + 5]),
                      "+v"(whh2[i + 6]), "+v"(whh2[i + 7]));
#pragma unroll
  for (int i = 0; i < 32; i += 8)
    asm volatile("" : "+v"(wxb[i]), "+v"(wxb[i + 1]), "+v"(wxb[i + 2]),
                      "+v"(wxb[i + 3]), "+v"(wxb[i + 4]), "+v"(wxb[i + 5]),
                      "+v"(wxb[i + 6]), "+v"(wxb[i + 7]));

  const float* __restrict__ xp = x + (size_t)n * 16;
  float c[8];
  int h2[4];
#pragma unroll
  for (int k = 0; k < 8; ++k) c[k] = 0.f;
#pragma unroll
  for (int j = 0; j < 4; ++j) h2[j] = 0;

  float xv = xp[0];
#pragma unroll 1
  for (int t = 0; t < 16; ++t) {
    float xn = xp[(t + 1) & 15];
    const int xt1 = packf16(xv, 1.f);
    float hn[8];
#pragma unroll
    for (int k = 0; k < 8; ++k) {
      float acc[4];
#pragma unroll
      for (int gi = 0; gi < 4; ++gi) {
        const int r = gi * 8 + k;
        float a = dot2(wxb[r], xt1, 0.f);
        a = dot2(whh2[r * 4 + 0], h2[0], a);
        a = dot2(whh2[r * 4 + 1], h2[1], a);
        a = dot2(whh2[r * 4 + 2], h2[2], a);
        a = dot2(whh2[r * 4 + 3], h2[3], a);
        acc[gi] = a;
      }
      float iv = fsig(acc[0]), fv = fsig(acc[1]);
      float gv = ftanh_(acc[2]), ov = fsig(acc[3]);
      c[k] = fmaf(fv, c[k], iv * gv);
      hn[k] = ov * ftanh_(c[k]);
    }
#pragma unroll
    for (int j = 0; j < 4; ++j) h2[j] = packf16(hn[2 * j], hn[2 * j + 1]);
    xv = xn;
  }
  int4 o;
  o.x = h2[0]; o.y = h2[1]; o.z = h2[2]; o.w = h2[3];
  h1out[n] = o;
}

// ---------------------------------------------------------------------------
// Pack kernel: identical to R11 (layouts correctness-proven there).
// ---------------------------------------------------------------------------
__global__ __launch_bounds__(512) void pack2_kernel(
    const float* __restrict__ Wih, const float* __restrict__ Whh,
    const float* __restrict__ bih, const float* __restrict__ bhh,
    int* __restrict__ wpack, float* __restrict__ bpack) {
  const int t = threadIdx.x;
  const int j = t >> 6, lane = t & 63, quad = lane >> 4, mA = lane & 15;
  const int kA = quad * 8;
  int* wp = wpack + t * 80;
#pragma unroll
  for (int g = 0; g < 4; ++g) {
    const int row = g * 128 + 16 * j + mA;  // gate-row in [0,512)
#pragma unroll
    for (int kt = 0; kt < 4; ++kt) {
      const float* src = Whh + (size_t)row * 128 + kt * 32 + kA;
#pragma unroll
      for (int pq = 0; pq < 4; ++pq)
        wp[(g * 5 + kt) * 4 + pq] = packf16(src[2 * pq], src[2 * pq + 1]);
    }
    if (quad == 0) {  // K-tile 4: k=128..135 -> Wih; other quads: zero pad
      const float* xi = Wih + (size_t)row * 8;
#pragma unroll
      for (int pq = 0; pq < 4; ++pq)
        wp[(g * 5 + 4) * 4 + pq] = packf16(xi[2 * pq], xi[2 * pq + 1]);
    } else {
#pragma unroll
      for (int pq = 0; pq < 4; ++pq) wp[(g * 5 + 4) * 4 + pq] = 0;
    }
  }
  float* bp = bpack + t * 16;
  const int mC = 16 * j + quad * 4;
#pragma unroll
  for (int g = 0; g < 4; ++g)
#pragma unroll
    for (int r = 0; r < 4; ++r)
      bp[g * 4 + r] = bih[g * 128 + mC + r] + bhh[g * 128 + mC + r];
}

// ---------------------------------------------------------------------------
// Layer 2 via MFMA — R11 structure with the serial chain fixed:
//  * x staged through a double-buffered 8-step LDS ring: loads issued at
//    chunk phase 0, written at phase 6 (~6 steps of slack) — the per-step
//    global load is OFF the barrier-to-barrier critical path (R11's main
//    stall: wave0's L2 latency gated all 8 waves at every barrier).
//  * bias folded into MFMA acc init (C-layout exact) — no per-step adds.
//  * H stride 168->136 f16 (68 dwords = 4*17, 17 odd -> b128 reads hit the
//    8-words/bank wave64 minimum evenly).
// One barrier/step. MFMA floor: 160 MFMA/step / 4 SIMD * 4.85 ~ 194 cyc.
// ---------------------------------------------------------------------------
__global__ __launch_bounds__(512, 2) void lstm2_kernel(
    const int4* __restrict__ h1, const int* __restrict__ wpack,
    const float* __restrict__ bpack, const float* __restrict__ Wd1,
    const float* __restrict__ bd1, const float* __restrict__ Wd2,
    const float* __restrict__ bd2, float* __restrict__ out) {
  __shared__ __align__(16) _Float16 H[2][16][136];    // 8.5 KB dbuf h
  __shared__ __align__(16) _Float16 XB[2][8][16][8];  // 8 KB x ring
  const int t = threadIdx.x;
  const int j = t >> 6, lane = t & 63, quad = lane >> 4, n = lane & 15;
  const int m0 = 16 * j + quad * 4;  // first hidden index of lane's C cells
  const int bb0 = blockIdx.x * 16;   // first batch of this block
  const bool stager = (t < 128);     // waves 0,1: x-ring staging duty
  const int sb = t & 15;             // stager's batch
  const int ss = t >> 4;             // stager's step-within-chunk (0..7)

  // A-frags + bias: volatile (load exactly once, final packed form).
  int4 wfrag[20];
  {
    const volatile int4* wp = (const volatile int4*)(wpack + t * 80);
#pragma unroll
    for (int i = 0; i < 20; ++i) {
      int4 v; v.x = wp[i].x; v.y = wp[i].y; v.z = wp[i].z; v.w = wp[i].w;
      wfrag[i] = v;
    }
  }
  float bias[16];
  {
    const volatile float* bp = bpack + t * 16;
#pragma unroll
    for (int i = 0; i < 16; ++i) bias[i] = bp[i];
  }

  // zero H (both buffers) and stage x chunk 0 into XB[0]
  {
    int* Hi = (int*)H;  // 2*16*136*2/4 = 2176 ints
    for (int i = t; i < 2176; i += 512) Hi[i] = 0;
  }
  int4 xh = {0, 0, 0, 0};
  if (stager) xh = h1[(size_t)(bb0 + sb) * 1024 + ss];
  __syncthreads();
  if (stager) *(int4*)&XB[0][ss][sb][0] = xh;
  __syncthreads();

  float cst[4] = {0.f, 0.f, 0.f, 0.f};

#pragma unroll 1
  for (int ts = 0; ts < 1024; ++ts) {
    const int p = ts & 1;
    const int ph = ts & 7;

    if (ph == 0 && stager) {  // issue loads for chunk (ts>>3)+1
      int s = ts + 8 + ss;
      if (s > 1023) s = 1023;  // tail: values never consumed
      xh = h1[(size_t)(bb0 + sb) * 1024 + s];
    }

    // B-frags: h from H[p], x from the ring (quads 1-3: A-frag is zero,
    // so their B content is don't-care -> same address = broadcast).
    half8 bf0 = *(const half8*)&H[p][n][0 * 32 + quad * 8];
    half8 bf1 = *(const half8*)&H[p][n][1 * 32 + quad * 8];
    half8 bf2 = *(const half8*)&H[p][n][2 * 32 + quad * 8];
    half8 bf3 = *(const half8*)&H[p][n][3 * 32 + quad * 8];
    half8 bf4 = *(const half8*)&XB[(ts >> 3) & 1][ph][n][0];

    f32x4 acc[4];
#pragma unroll
    for (int g = 0; g < 4; ++g) {
      f32x4 a;  // bias folded into acc init (C cell (row m0+r, col n))
      a[0] = bias[g * 4 + 0]; a[1] = bias[g * 4 + 1];
      a[2] = bias[g * 4 + 2]; a[3] = bias[g * 4 + 3];
      a = __builtin_amdgcn_mfma_f32_16x16x32_f16(
          __builtin_bit_cast(half8, wfrag[g * 5 + 0]), bf0, a, 0, 0, 0);
      a = __builtin_amdgcn_mfma_f32_16x16x32_f16(
          __builtin_bit_cast(half8, wfrag[g * 5 + 1]), bf1, a, 0, 0, 0);
      a = __builtin_amdgcn_mfma_f32_16x16x32_f16(
          __builtin_bit_cast(half8, wfrag[g * 5 + 2]), bf2, a, 0, 0, 0);
      a = __builtin_amdgcn_mfma_f32_16x16x32_f16(
          __builtin_bit_cast(half8, wfrag[g * 5 + 3]), bf3, a, 0, 0, 0);
      a = __builtin_amdgcn_mfma_f32_16x16x32_f16(
          __builtin_bit_cast(half8, wfrag[g * 5 + 4]), bf4, a, 0, 0, 0);
      acc[g] = a;
    }

    // state update for this lane's 4 cells (hidden m0+r, batch n)
    float hx[4];
#pragma unroll
    for (int r = 0; r < 4; ++r) {
      float iv = fsig(acc[0][r]);
      float fv = fsig(acc[1][r]);
      float gv = ftanh_(acc[2][r]);
      float ov = fsig(acc[3][r]);
      cst[r] = fmaf(fv, cst[r], iv * gv);
      hx[r] = ov * ftanh_(cst[r]);
    }
    int2 hw;
    hw.x = packf16(hx[0], hx[1]);
    hw.y = packf16(hx[2], hx[3]);
    *(int2*)&H[1 - p][n][m0] = hw;

    if (ph == 6 && stager)  // ring write: ~6 steps after issue, vmcnt ~free
      *(int4*)&XB[((ts >> 3) + 1) & 1][ss][sb][0] = xh;

    __syncthreads();  // the only barrier per step
  }

  // Epilogue: h_T is in H[0] (loop parity). Wave j: batches 2j, 2j+1.
#pragma unroll
  for (int bi = 0; bi < 2; ++bi) {
    const int nn = 2 * j + bi;
    float a = bd1[lane];
    for (int k = 0; k < 128; ++k)
      a = fmaf(Wd1[lane * 128 + k], (float)H[0][nn][k], a);
    float v = a * Wd2[lane];
#pragma unroll
    for (int off = 32; off > 0; off >>= 1) v += __shfl_down(v, off);
    if (lane == 0) out[bb0 + nn] = v + bd2[0];
  }
}

extern "C" void kernel_launch(void* const* d_in, const int* in_sizes, int n_in,
                              void* d_out, int out_size, void* d_ws, size_t ws_size,
                              hipStream_t stream) {
  const float* x    = (const float*)d_in[0];
  // d_in[1] is the unused python scalar `data`
  const float* Wih1 = (const float*)d_in[2];
  const float* Whh1 = (const float*)d_in[3];
  const float* bih1 = (const float*)d_in[4];
  const float* bhh1 = (const float*)d_in[5];
  const float* Wih2 = (const float*)d_in[6];
  const float* Whh2 = (const float*)d_in[7];
  const float* bih2 = (const float*)d_in[8];
  const float* bhh2 = (const float*)d_in[9];
  const float* W1   = (const float*)d_in[10];
  const float* b1   = (const float*)d_in[11];
  const float* W2   = (const float*)d_in[12];
  const float* b2   = (const float*)d_in[13];
  float* out = (float*)d_out;

  // workspace layout
  char* ws = (char*)d_ws;
  int4*  h1    = (int4*)ws;                              // 4 MB
  int*   wpack = (int*)(ws + (4 << 20));                 // 512*80*4 = 160 KB
  float* bpack = (float*)(ws + (4 << 20) + (160 << 10)); // 32 KB

  lstm1_kernel<<<1024, 256, 0, stream>>>(x, Wih1, Whh1, bih1, bhh1, h1);
  pack2_kernel<<<1, 512, 0, stream>>>(Wih2, Whh2, bih2, bhh2, wpack, bpack);
  lstm2_kernel<<<16, 512, 0, stream>>>(h1, wpack, bpack, W1, b1, W2, b2, out);
}

// Round 13
// 899.537 us; speedup vs baseline: 2.0100x; 1.9113x over previous
//
#include <hip/hip_runtime.h>
#include <cstdint>

typedef _Float16 f16x2 __attribute__((ext_vector_type(2)));

// Clamp-free fast activations: gate pre-activations here are |x| <~ 15.
__device__ __forceinline__ float fsig(float x) {
  return __fdividef(1.f, 1.f + __expf(-x));
}
__device__ __forceinline__ float ftanh_(float x) {
  return fmaf(2.f, fsig(x + x), -1.f);
}
__device__ __forceinline__ int packf16(float a, float b) {
  f16x2 p; p.x = (_Float16)a; p.y = (_Float16)b;
  return __builtin_bit_cast(int, p);
}
__device__ __forceinline__ float dot2(int w, int h, float acc) {
  return __builtin_amdgcn_fdot2(__builtin_bit_cast(f16x2, w),
                                __builtin_bit_cast(f16x2, h), acc, false);
}
template <int PAT>
__device__ __forceinline__ float swzf(float v) {
  return __int_as_float(__builtin_amdgcn_ds_swizzle(__float_as_int(v), PAT));
}
#define SWZ_X1 0x041F  // xor lane^1 (BitMode)
#define SWZ_X2 0x081F  // xor lane^2

// ---------------------------------------------------------------------------
// Layer 1: frozen (R10/R12 version, ~85-120 us) to keep attribution on lstm2.
// ---------------------------------------------------------------------------
__global__ __launch_bounds__(256, 2) void lstm1_kernel(
    const float* __restrict__ x, const float* __restrict__ Wih,
    const float* __restrict__ Whh, const float* __restrict__ bih,
    const float* __restrict__ bhh, int4* __restrict__ h1out) {
  const int n = blockIdx.x * 256 + threadIdx.x;  // chain id = b*S + s

  int whh2[128];
#pragma unroll
  for (int r = 0; r < 32; ++r) {
#pragma unroll
    for (int j = 0; j < 4; ++j) {
      float2 v = ((const float2*)(Whh + r * 8))[j];
      whh2[r * 4 + j] = packf16(v.x, v.y);
    }
  }
  int wxb[32];
#pragma unroll
  for (int r = 0; r < 32; ++r) wxb[r] = packf16(Wih[r], bih[r] + bhh[r]);

#pragma unroll
  for (int i = 0; i < 128; i += 8)
    asm volatile("" : "+v"(whh2[i]), "+v"(whh2[i + 1]), "+v"(whh2[i + 2]),
                      "+v"(whh2[i + 3]), "+v"(whh2[i + 4]), "+v"(whh2[i + 5]),
                      "+v"(whh2[i + 6]), "+v"(whh2[i + 7]));
#pragma unroll
  for (int i = 0; i < 32; i += 8)
    asm volatile("" : "+v"(wxb[i]), "+v"(wxb[i + 1]), "+v"(wxb[i + 2]),
                      "+v"(wxb[i + 3]), "+v"(wxb[i + 4]), "+v"(wxb[i + 5]),
                      "+v"(wxb[i + 6]), "+v"(wxb[i + 7]));

  const float* __restrict__ xp = x + (size_t)n * 16;
  float c[8];
  int h2[4];
#pragma unroll
  for (int k = 0; k < 8; ++k) c[k] = 0.f;
#pragma unroll
  for (int j = 0; j < 4; ++j) h2[j] = 0;

  float xv = xp[0];
#pragma unroll 1
  for (int t = 0; t < 16; ++t) {
    float xn = xp[(t + 1) & 15];
    const int xt1 = packf16(xv, 1.f);
    float hn[8];
#pragma unroll
    for (int k = 0; k < 8; ++k) {
      float acc[4];
#pragma unroll
      for (int gi = 0; gi < 4; ++gi) {
        const int r = gi * 8 + k;
        float a = dot2(wxb[r], xt1, 0.f);
        a = dot2(whh2[r * 4 + 0], h2[0], a);
        a = dot2(whh2[r * 4 + 1], h2[1], a);
        a = dot2(whh2[r * 4 + 2], h2[2], a);
        a = dot2(whh2[r * 4 + 3], h2[3], a);
        acc[gi] = a;
      }
      float iv = fsig(acc[0]), fv = fsig(acc[1]);
      float gv = ftanh_(acc[2]), ov = fsig(acc[3]);
      c[k] = fmaf(fv, c[k], iv * gv);
      hn[k] = ov * ftanh_(c[k]);
    }
#pragma unroll
    for (int j = 0; j < 4; ++j) h2[j] = packf16(hn[2 * j], hn[2 * j + 1]);
    xv = xn;
  }
  int4 o;
  o.x = h2[0]; o.y = h2[1]; o.z = h2[2]; o.w = h2[3];
  h1out[n] = o;
}

// ---------------------------------------------------------------------------
// Layer 2: R9 quad-split (best measured: 782 us) with ONE change — the
// entire x sequence (16 KB) is staged into LDS up front, so the recurrent
// loop contains ZERO global/scalar loads. Rationale (R12 post-mortem +
// m97): __syncthreads lowers to `s_waitcnt vmcnt(0) lgkmcnt(0); s_barrier`,
// which force-drains any in-flight global/s_load at EVERY step's barrier —
// R9's "prefetched" uniform x s_load was re-exposed (~L2 latency) every
// step. With x in LDS, the loop's only memory ops are short LDS accesses
// that the barrier would legitimately wait on anyway.
// Thread (m=t>>2, q=t&3) holds K-quarter q of all four gate rows of index m;
// transpose-reduce via ds_swizzle; c/h replicated per quad; one barrier/step.
// ---------------------------------------------------------------------------
__global__ __launch_bounds__(512, 2) void lstm2_kernel(
    const int4* __restrict__ h1, const float* __restrict__ Wih,
    const float* __restrict__ Whh, const float* __restrict__ bih,
    const float* __restrict__ bhh, const float* __restrict__ Wd1,
    const float* __restrict__ bd1, const float* __restrict__ Wd2,
    const float* __restrict__ bd2, float* __restrict__ out) {
  __shared__ __align__(16) _Float16 sH[2][128];  // 512 B double-buffered h
  __shared__ __align__(16) int4 sX[1024];        // 16 KB: full x sequence
  const int b = blockIdx.x;
  const int t = threadIdx.x;
  const int m = t >> 2;  // hidden index
  const int q = t & 3;   // K-quarter and result slot
  const int G = ((q & 1) << 1) | (q >> 1);  // gate this thread finalizes
  const bool sel0 = (q & 1) != 0;
  const bool sel1 = (q & 2) != 0;
  const bool isq0 = (q == 0);
  const bool isq1 = (q == 1);  // G==2 (tanh gate)

  {  // stage the whole x sequence once (coalesced; outside the loop)
    const int4* xq = h1 + (size_t)b * 1024;
    sX[t] = xq[t];
    sX[t + 512] = xq[t + 512];
  }

  // K-quarter q of all four gate rows of index m: w[g*16+j]
  int w[64];
#pragma unroll
  for (int g = 0; g < 4; ++g) {
    const float2* p = (const float2*)(Whh + (size_t)(g * 128 + m) * 128 + q * 32);
#pragma unroll
    for (int j = 0; j < 16; ++j) {
      float2 v = p[j];
      w[g * 16 + j] = packf16(v.x, v.y);
    }
  }

  // x-row + bias for the gate this thread finalizes (row G*128+m)
  int wig[4];
  {
    const float2* pi = (const float2*)(Wih + (size_t)(G * 128 + m) * 8);
#pragma unroll
    for (int j = 0; j < 4; ++j) {
      float2 v = pi[j];
      wig[j] = packf16(v.x, v.y);
    }
  }
  const float bias = bih[G * 128 + m] + bhh[G * 128 + m];

  int hq[16];  // this thread's h-quarter (32 f16)
#pragma unroll
  for (int i = 0; i < 16; ++i) hq[i] = 0;
  float c = 0.f;  // cell state for index m (replicated across the quad)

  __syncthreads();  // sX visible
  int4 xc = sX[0];  // LDS same-address broadcast

#pragma unroll 1
  for (int ts = 0; ts < 1024; ++ts) {
    // x-part + bias for this thread's final gate
    float bx = bias;
    bx = dot2(wig[0], xc.x, bx);
    bx = dot2(wig[1], xc.y, bx);
    bx = dot2(wig[2], xc.z, bx);
    bx = dot2(wig[3], xc.w, bx);

    // quarter-dots of all 4 gate rows (64 dot2, 4 independent chains)
    float R0 = 0.f, R1 = 0.f, R2 = 0.f, R3 = 0.f;
#pragma unroll
    for (int j = 0; j < 16; ++j) {
      R0 = dot2(w[j], hq[j], R0);
      R1 = dot2(w[16 + j], hq[j], R1);
      R2 = dot2(w[32 + j], hq[j], R2);
      R3 = dot2(w[48 + j], hq[j], R3);
    }
    // transpose-reduce across the quad: thread q ends with gate G's full sum
    float s0 = sel0 ? R0 : R2, s1 = sel0 ? R1 : R3;   // send
    float k0 = sel0 ? R2 : R0, k1 = sel0 ? R3 : R1;   // keep
    float S0 = k0 + swzf<SWZ_X1>(s0);
    float S1 = k1 + swzf<SWZ_X1>(s1);
    float s2 = sel1 ? S0 : S1;
    float k2 = sel1 ? S1 : S0;
    float S = k2 + swzf<SWZ_X2>(s2) + bx;

    // activation: gate G (tanh iff q==1) via 2*sig(2x)-1
    float u = isq1 ? (S + S) : S;
    float sg = fsig(u);
    float act = isq1 ? fmaf(2.f, sg, -1.f) : sg;

    // gather all 4 activated gates into every quad lane
    float v0 = act;
    float v1 = swzf<SWZ_X1>(v0);
    float v2 = swzf<SWZ_X2>(v0);
    float v3 = swzf<SWZ_X2>(v1);
    float p01 = sel0 ? v1 : v0, p23 = sel0 ? v3 : v2;
    float q01 = sel0 ? v0 : v1, q23 = sel0 ? v2 : v3;
    float iv = sel1 ? p23 : p01;
    float fv = sel1 ? p01 : p23;
    float gv = sel1 ? q23 : q01;
    float ov = sel1 ? q01 : q23;

    c = fmaf(fv, c, iv * gv);
    float hx = ov * ftanh_(c);
    if (isq0) sH[ts & 1][m] = (_Float16)hx;  // one writer per index
    __syncthreads();                         // the only barrier per step

    {  // refresh this thread's h-quarter (4 x ds_read_b128) and prefetch
       // next step's x from LDS (broadcast) — both off the top-of-step path
      const int4* src = (const int4*)(&sH[ts & 1][q * 32]);
      int4 A = src[0], B = src[1], C = src[2], D = src[3];
      hq[0] = A.x;  hq[1] = A.y;  hq[2] = A.z;  hq[3] = A.w;
      hq[4] = B.x;  hq[5] = B.y;  hq[6] = B.z;  hq[7] = B.w;
      hq[8] = C.x;  hq[9] = C.y;  hq[10] = C.z; hq[11] = C.w;
      hq[12] = D.x; hq[13] = D.y; hq[14] = D.z; hq[15] = D.w;
      xc = sX[ts < 1023 ? ts + 1 : 1023];
    }
  }

  // Epilogue: out[b] = (h @ Wd1.T + bd1) @ Wd2.T + bd2; h_T is in sH[1].
  if (t < 64) {
    float a = bd1[t];
#pragma unroll
    for (int k = 0; k < 128; ++k)
      a = fmaf(Wd1[t * 128 + k], (float)sH[1][k], a);
    float v = a * Wd2[t];
#pragma unroll
    for (int off = 32; off > 0; off >>= 1) v += __shfl_down(v, off);
    if (t == 0) out[b] = v + bd2[0];
  }
}

extern "C" void kernel_launch(void* const* d_in, const int* in_sizes, int n_in,
                              void* d_out, int out_size, void* d_ws, size_t ws_size,
                              hipStream_t stream) {
  const float* x    = (const float*)d_in[0];
  // d_in[1] is the unused python scalar `data`
  const float* Wih1 = (const float*)d_in[2];
  const float* Whh1 = (const float*)d_in[3];
  const float* bih1 = (const float*)d_in[4];
  const float* bhh1 = (const float*)d_in[5];
  const float* Wih2 = (const float*)d_in[6];
  const float* Whh2 = (const float*)d_in[7];
  const float* bih2 = (const float*)d_in[8];
  const float* bhh2 = (const float*)d_in[9];
  const float* W1   = (const float*)d_in[10];
  const float* b1   = (const float*)d_in[11];
  const float* W2   = (const float*)d_in[12];
  const float* b2   = (const float*)d_in[13];
  float* out = (float*)d_out;

  int4* h1 = (int4*)d_ws;  // 262144 chains x 8 f16 = 4 MB scratch

  lstm1_kernel<<<1024, 256, 0, stream>>>(x, Wih1, Whh1, bih1, bhh1, h1);
  lstm2_kernel<<<256, 512, 0, stream>>>(h1, Wih2, Whh2, bih2, bhh2,
                                        W1, b1, W2, b2, out);
}

// Round 14
// 814.873 us; speedup vs baseline: 2.2189x; 1.1039x over previous
//
#include <hip/hip_runtime.h>
#include <cstdint>

typedef _Float16 f16x2 __attribute__((ext_vector_type(2)));

// Clamp-free fast activations: gate pre-activations here are |x| <~ 15.
__device__ __forceinline__ float fsig(float x) {
  return __fdividef(1.f, 1.f + __expf(-x));
}
__device__ __forceinline__ float ftanh_(float x) {
  return fmaf(2.f, fsig(x + x), -1.f);
}
__device__ __forceinline__ int packf16(float a, float b) {
  f16x2 p; p.x = (_Float16)a; p.y = (_Float16)b;
  return __builtin_bit_cast(int, p);
}
__device__ __forceinline__ float dot2(int w, int h, float acc) {
  return __builtin_amdgcn_fdot2(__builtin_bit_cast(f16x2, w),
                                __builtin_bit_cast(f16x2, h), acc, false);
}
// Quad-lane permute via DPP: VALU-latency (~4 cyc) vs ds_swizzle's LDS
// latency (~100+ cyc). q = t&3 lanes ARE the DPP quads, so quad_perm
// reproduces xor1/xor2 exactly.
template <int CTRL>
__device__ __forceinline__ float qp(float v) {
  return __int_as_float(__builtin_amdgcn_update_dpp(
      0, __float_as_int(v), CTRL, 0xF, 0xF, true));
}
#define QP_X1 0xB1  // quad_perm [1,0,3,2]  (lane ^ 1)
#define QP_X2 0x4E  // quad_perm [2,3,0,1]  (lane ^ 2)

// ---------------------------------------------------------------------------
// Layer 1: frozen (R10..R13 version, ~110 us) to keep attribution on lstm2.
// ---------------------------------------------------------------------------
__global__ __launch_bounds__(256, 2) void lstm1_kernel(
    const float* __restrict__ x, const float* __restrict__ Wih,
    const float* __restrict__ Whh, const float* __restrict__ bih,
    const float* __restrict__ bhh, int4* __restrict__ h1out) {
  const int n = blockIdx.x * 256 + threadIdx.x;  // chain id = b*S + s

  int whh2[128];
#pragma unroll
  for (int r = 0; r < 32; ++r) {
#pragma unroll
    for (int j = 0; j < 4; ++j) {
      float2 v = ((const float2*)(Whh + r * 8))[j];
      whh2[r * 4 + j] = packf16(v.x, v.y);
    }
  }
  int wxb[32];
#pragma unroll
  for (int r = 0; r < 32; ++r) wxb[r] = packf16(Wih[r], bih[r] + bhh[r]);

#pragma unroll
  for (int i = 0; i < 128; i += 8)
    asm volatile("" : "+v"(whh2[i]), "+v"(whh2[i + 1]), "+v"(whh2[i + 2]),
                      "+v"(whh2[i + 3]), "+v"(whh2[i + 4]), "+v"(whh2[i + 5]),
                      "+v"(whh2[i + 6]), "+v"(whh2[i + 7]));
#pragma unroll
  for (int i = 0; i < 32; i += 8)
    asm volatile("" : "+v"(wxb[i]), "+v"(wxb[i + 1]), "+v"(wxb[i + 2]),
                      "+v"(wxb[i + 3]), "+v"(wxb[i + 4]), "+v"(wxb[i + 5]),
                      "+v"(wxb[i + 6]), "+v"(wxb[i + 7]));

  const float* __restrict__ xp = x + (size_t)n * 16;
  float c[8];
  int h2[4];
#pragma unroll
  for (int k = 0; k < 8; ++k) c[k] = 0.f;
#pragma unroll
  for (int j = 0; j < 4; ++j) h2[j] = 0;

  float xv = xp[0];
#pragma unroll 1
  for (int t = 0; t < 16; ++t) {
    float xn = xp[(t + 1) & 15];
    const int xt1 = packf16(xv, 1.f);
    float hn[8];
#pragma unroll
    for (int k = 0; k < 8; ++k) {
      float acc[4];
#pragma unroll
      for (int gi = 0; gi < 4; ++gi) {
        const int r = gi * 8 + k;
        float a = dot2(wxb[r], xt1, 0.f);
        a = dot2(whh2[r * 4 + 0], h2[0], a);
        a = dot2(whh2[r * 4 + 1], h2[1], a);
        a = dot2(whh2[r * 4 + 2], h2[2], a);
        a = dot2(whh2[r * 4 + 3], h2[3], a);
        acc[gi] = a;
      }
      float iv = fsig(acc[0]), fv = fsig(acc[1]);
      float gv = ftanh_(acc[2]), ov = fsig(acc[3]);
      c[k] = fmaf(fv, c[k], iv * gv);
      hn[k] = ov * ftanh_(c[k]);
    }
#pragma unroll
    for (int j = 0; j < 4; ++j) h2[j] = packf16(hn[2 * j], hn[2 * j + 1]);
    xv = xn;
  }
  int4 o;
  o.x = h2[0]; o.y = h2[1]; o.z = h2[2]; o.w = h2[3];
  h1out[n] = o;
}

// ---------------------------------------------------------------------------
// Layer 2: R13 structure with ONE change — the 6 ds_swizzle hops in the
// reduce/gather path are replaced by DPP quad_perm (VALU latency ~4 cyc vs
// LDS ~100+). R13 post-mortem: 1851 cyc/step = ~580 cyc VALU issue (incl.
// AGPR-read tax on the parked weights) + ~400-500 cyc of serial ds_swizzle
// latency + barrier/LDS floor; this removes the swizzle-latency term.
// Everything else (x staged in LDS, quad K-split, one barrier/step) is
// byte-identical to R13.
// ---------------------------------------------------------------------------
__global__ __launch_bounds__(512, 2) void lstm2_kernel(
    const int4* __restrict__ h1, const float* __restrict__ Wih,
    const float* __restrict__ Whh, const float* __restrict__ bih,
    const float* __restrict__ bhh, const float* __restrict__ Wd1,
    const float* __restrict__ bd1, const float* __restrict__ Wd2,
    const float* __restrict__ bd2, float* __restrict__ out) {
  __shared__ __align__(16) _Float16 sH[2][128];  // 512 B double-buffered h
  __shared__ __align__(16) int4 sX[1024];        // 16 KB: full x sequence
  const int b = blockIdx.x;
  const int t = threadIdx.x;
  const int m = t >> 2;  // hidden index
  const int q = t & 3;   // K-quarter and result slot (= DPP quad lane)
  const int G = ((q & 1) << 1) | (q >> 1);  // gate this thread finalizes
  const bool sel0 = (q & 1) != 0;
  const bool sel1 = (q & 2) != 0;
  const bool isq0 = (q == 0);
  const bool isq1 = (q == 1);  // G==2 (tanh gate)

  {  // stage the whole x sequence once (coalesced; outside the loop)
    const int4* xq = h1 + (size_t)b * 1024;
    sX[t] = xq[t];
    sX[t + 512] = xq[t + 512];
  }

  // K-quarter q of all four gate rows of index m: w[g*16+j]
  int w[64];
#pragma unroll
  for (int g = 0; g < 4; ++g) {
    const float2* p = (const float2*)(Whh + (size_t)(g * 128 + m) * 128 + q * 32);
#pragma unroll
    for (int j = 0; j < 16; ++j) {
      float2 v = p[j];
      w[g * 16 + j] = packf16(v.x, v.y);
    }
  }

  // x-row + bias for the gate this thread finalizes (row G*128+m)
  int wig[4];
  {
    const float2* pi = (const float2*)(Wih + (size_t)(G * 128 + m) * 8);
#pragma unroll
    for (int j = 0; j < 4; ++j) {
      float2 v = pi[j];
      wig[j] = packf16(v.x, v.y);
    }
  }
  const float bias = bih[G * 128 + m] + bhh[G * 128 + m];

  int hq[16];  // this thread's h-quarter (32 f16)
#pragma unroll
  for (int i = 0; i < 16; ++i) hq[i] = 0;
  float c = 0.f;  // cell state for index m (replicated across the quad)

  __syncthreads();  // sX visible
  int4 xc = sX[0];  // LDS same-address broadcast

#pragma unroll 1
  for (int ts = 0; ts < 1024; ++ts) {
    // x-part + bias for this thread's final gate
    float bx = bias;
    bx = dot2(wig[0], xc.x, bx);
    bx = dot2(wig[1], xc.y, bx);
    bx = dot2(wig[2], xc.z, bx);
    bx = dot2(wig[3], xc.w, bx);

    // quarter-dots of all 4 gate rows (64 dot2, 4 independent chains)
    float R0 = 0.f, R1 = 0.f, R2 = 0.f, R3 = 0.f;
#pragma unroll
    for (int j = 0; j < 16; ++j) {
      R0 = dot2(w[j], hq[j], R0);
      R1 = dot2(w[16 + j], hq[j], R1);
      R2 = dot2(w[32 + j], hq[j], R2);
      R3 = dot2(w[48 + j], hq[j], R3);
    }
    // transpose-reduce across the quad (DPP): thread q ends with gate G's sum
    float s0 = sel0 ? R0 : R2, s1 = sel0 ? R1 : R3;   // send
    float k0 = sel0 ? R2 : R0, k1 = sel0 ? R3 : R1;   // keep
    float S0 = k0 + qp<QP_X1>(s0);
    float S1 = k1 + qp<QP_X1>(s1);
    float s2 = sel1 ? S0 : S1;
    float k2 = sel1 ? S1 : S0;
    float S = k2 + qp<QP_X2>(s2) + bx;

    // activation: gate G (tanh iff q==1) via 2*sig(2x)-1
    float u = isq1 ? (S + S) : S;
    float sg = fsig(u);
    float act = isq1 ? fmaf(2.f, sg, -1.f) : sg;

    // gather all 4 activated gates into every quad lane (DPP)
    float v0 = act;
    float v1 = qp<QP_X1>(v0);
    float v2 = qp<QP_X2>(v0);
    float v3 = qp<QP_X2>(v1);
    float p01 = sel0 ? v1 : v0, p23 = sel0 ? v3 : v2;
    float q01 = sel0 ? v0 : v1, q23 = sel0 ? v2 : v3;
    float iv = sel1 ? p23 : p01;
    float fv = sel1 ? p01 : p23;
    float gv = sel1 ? q23 : q01;
    float ov = sel1 ? q01 : q23;

    c = fmaf(fv, c, iv * gv);
    float hx = ov * ftanh_(c);
    if (isq0) sH[ts & 1][m] = (_Float16)hx;  // one writer per index
    __syncthreads();                         // the only barrier per step

    {  // refresh this thread's h-quarter (4 x ds_read_b128) and prefetch
       // next step's x from LDS (broadcast)
      const int4* src = (const int4*)(&sH[ts & 1][q * 32]);
      int4 A = src[0], B = src[1], C = src[2], D = src[3];
      hq[0] = A.x;  hq[1] = A.y;  hq[2] = A.z;  hq[3] = A.w;
      hq[4] = B.x;  hq[5] = B.y;  hq[6] = B.z;  hq[7] = B.w;
      hq[8] = C.x;  hq[9] = C.y;  hq[10] = C.z; hq[11] = C.w;
      hq[12] = D.x; hq[13] = D.y; hq[14] = D.z; hq[15] = D.w;
      xc = sX[ts < 1023 ? ts + 1 : 1023];
    }
  }

  // Epilogue: out[b] = (h @ Wd1.T + bd1) @ Wd2.T + bd2; h_T is in sH[1].
  if (t < 64) {
    float a = bd1[t];
#pragma unroll
    for (int k = 0; k < 128; ++k)
      a = fmaf(Wd1[t * 128 + k], (float)sH[1][k], a);
    float v = a * Wd2[t];
#pragma unroll
    for (int off = 32; off > 0; off >>= 1) v += __shfl_down(v, off);
    if (t == 0) out[b] = v + bd2[0];
  }
}

extern "C" void kernel_launch(void* const* d_in, const int* in_sizes, int n_in,
                              void* d_out, int out_size, void* d_ws, size_t ws_size,
                              hipStream_t stream) {
  const float* x    = (const float*)d_in[0];
  // d_in[1] is the unused python scalar `data`
  const float* Wih1 = (const float*)d_in[2];
  const float* Whh1 = (const float*)d_in[3];
  const float* bih1 = (const float*)d_in[4];
  const float* bhh1 = (const float*)d_in[5];
  const float* Wih2 = (const float*)d_in[6];
  const float* Whh2 = (const float*)d_in[7];
  const float* bih2 = (const float*)d_in[8];
  const float* bhh2 = (const float*)d_in[9];
  const float* W1   = (const float*)d_in[10];
  const float* b1   = (const float*)d_in[11];
  const float* W2   = (const float*)d_in[12];
  const float* b2   = (const float*)d_in[13];
  float* out = (float*)d_out;

  int4* h1 = (int4*)d_ws;  // 262144 chains x 8 f16 = 4 MB scratch

  lstm1_kernel<<<1024, 256, 0, stream>>>(x, Wih1, Whh1, bih1, bhh1, h1);
  lstm2_kernel<<<256, 512, 0, stream>>>(h1, Wih2, Whh2, bih2, bhh2,
                                        W1, b1, W2, b2, out);
}